// Round 2
// baseline (4340.295 us; speedup 1.0000x reference)
//
#include <hip/hip_runtime.h>

// ---------------------------------------------------------------------------
// FGSW-MSA pipeline, round 2: fused per-window conv_q+conv_kv+attention.
// Workspace (bytes):
//   qn   (2,128,128,64)  bf16 @ 0           4,194,304
//   kvn  (6,128,128,64)  bf16 @ 4,194,304   12,582,912
//   ao   (2,128,128,512) bf16 @ 16,777,216  33,554,432
//   wqp  (576,512)  f32       @ 50,331,648   1,179,648
//   wkvp (576,1024) f32       @ 51,511,296   2,359,296
//   wop  (4608,64)  f32       @ 53,870,592   1,179,648
// total 55,050,240 B (~52.5 MB)
// ---------------------------------------------------------------------------

__device__ __forceinline__ float bs2f(unsigned short s) {
    return __uint_as_float(((unsigned int)s) << 16);
}
__device__ __forceinline__ unsigned short f2bs(float f) {
    unsigned int u = __float_as_uint(f);
    u += 0x7fffu + ((u >> 16) & 1u);   // RNE
    return (unsigned short)(u >> 16);
}

// ------------------------- LayerNorm (q path) ------------------------------
__global__ __launch_bounds__(256) void ln_q_kernel(
    const float* __restrict__ q_inp, const float* __restrict__ g,
    const float* __restrict__ b, unsigned short* __restrict__ qn)
{
    int wid  = (blockIdx.x * 256 + threadIdx.x) >> 6;   // 0..32767
    int lane = threadIdx.x & 63;
    int pix  = wid & 16383;
    int bb   = wid >> 14;
    float val = q_inp[(bb * 64 + lane) * 16384 + pix];
    float s = val;
    #pragma unroll
    for (int m = 1; m < 64; m <<= 1) s += __shfl_xor(s, m);
    float mu = s * (1.f / 64.f);
    float d = val - mu;
    float s2 = d * d;
    #pragma unroll
    for (int m = 1; m < 64; m <<= 1) s2 += __shfl_xor(s2, m);
    float o = d * rsqrtf(s2 * (1.f / 64.f) + 1e-5f) * g[lane] + b[lane];
    qn[wid * 64 + lane] = f2bs(o);
}

// --------------------- nearest-warp + LayerNorm (kv path) ------------------
__global__ __launch_bounds__(256) void warp_ln_kv_kernel(
    const float* __restrict__ k_inp, const float* __restrict__ flow_f,
    const float* __restrict__ flow_b, const float* __restrict__ g,
    const float* __restrict__ b, unsigned short* __restrict__ kvn)
{
    int wid  = (blockIdx.x * 256 + threadIdx.x) >> 6;   // ((b*3+f)*128+y)*128+x
    int lane = threadIdx.x & 63;
    int x  = wid & 127;
    int y  = (wid >> 7) & 127;
    int bf = wid >> 14;                  // 0..5
    int f  = bf % 3, bb = bf / 3;
    float val;
    if (f == 1) {
        val = k_inp[(bf * 64 + lane) * 16384 + y * 128 + x];
    } else {
        const float* fl = (f == 0) ? flow_f : flow_b;
        float fx = fl[(bb * 2 + 0) * 16384 + y * 128 + x];
        float fy = fl[(bb * 2 + 1) * 16384 + y * 128 + x];
        int ix = (int)rintf((float)x + fx);   // round-half-even == jnp.round
        int iy = (int)rintf((float)y + fy);
        if (ix >= 0 && ix < 128 && iy >= 0 && iy < 128)
            val = k_inp[(bf * 64 + lane) * 16384 + iy * 128 + ix];
        else
            val = 0.f;
    }
    float s = val;
    #pragma unroll
    for (int m = 1; m < 64; m <<= 1) s += __shfl_xor(s, m);
    float mu = s * (1.f / 64.f);
    float d = val - mu;
    float s2 = d * d;
    #pragma unroll
    for (int m = 1; m < 64; m <<= 1) s2 += __shfl_xor(s2, m);
    float o = d * rsqrtf(s2 * (1.f / 64.f) + 1e-5f) * g[lane] + b[lane];
    kvn[wid * 64 + lane] = f2bs(o);
}

// --------------------------- weight repack ---------------------------------
// W (OC, IC, 3, 3) -> wp[(ic*9+t)*OC + oc]
__global__ __launch_bounds__(256) void repack_kernel(
    const float* __restrict__ w, float* __restrict__ wp, int OC, int KK)
{
    int idx = blockIdx.x * 256 + threadIdx.x;
    if (idx >= OC * KK) return;
    int oc = idx / KK, r = idx - oc * KK;
    wp[r * OC + oc] = w[idx];
}

#define FMA8(A, W0, W1, ACC)                                                  \
    ACC[0] += (A) * W0.x; ACC[1] += (A) * W0.y; ACC[2] += (A) * W0.z;         \
    ACC[3] += (A) * W0.w; ACC[4] += (A) * W1.x; ACC[5] += (A) * W1.y;         \
    ACC[6] += (A) * W1.z; ACC[7] += (A) * W1.w;

// ----------------- fused conv_q + conv_kv + window attention ---------------
// grid (1024, 2): blockIdx.x = wy*32+wx, blockIdx.y = b.  block = 256 thr.
// LDS union (51,968 B):
//   kvpatch u16[3][64][48] @0      (18,432)   [ic*48 + hy*8 + hx], hy,hx in 0..5
//   qls     u16[16][520]   @18432  (16,640)   q rows (scaled 1/8), all heads
//   kls     u16[48][72]    @35072  ( 6,912)   per-head k
//   vls     u16[48][72]    @41984  ( 6,912)   per-head v
//   atl     f32[16][48]    @48896  ( 3,072)
//   qpatch  u16[64][48]    = kls region (6,144<=6,912), dead before head loop
__global__ __launch_bounds__(256) void fused_attn_kernel(
    const unsigned short* __restrict__ qn,
    const unsigned short* __restrict__ kvn,
    const float* __restrict__ wqp,
    const float* __restrict__ wkvp,
    const float* __restrict__ sa,
    unsigned short* __restrict__ ao)
{
    __shared__ __align__(16) unsigned char smem[51968];
    unsigned short* kvpatch = (unsigned short*)smem;
    unsigned short* qls     = (unsigned short*)(smem + 18432);
    unsigned short* kls     = (unsigned short*)(smem + 35072);
    unsigned short* vls     = (unsigned short*)(smem + 41984);
    float*          atl     = (float*)(smem + 48896);
    unsigned short* qpatch  = kls;

    const int tid = threadIdx.x;
    const int wx = blockIdx.x & 31, wy = blockIdx.x >> 5;
    const int bb = blockIdx.y;
    const int gx0 = wx * 4 - 1, gy0 = wy * 4 - 1;

    // ---- stage input patches (6x6 halo, bf16, [ic][hy*8+hx] layout) ----
    for (int u = tid; u < 3 * 288; u += 256) {
        int f = u / 288, rest = u - f * 288;
        int p = rest >> 3, seg = rest & 7;
        int hy = p / 6, hx = p - hy * 6;
        int gy = gy0 + hy, gx = gx0 + hx;
        uint4 v = make_uint4(0u, 0u, 0u, 0u);
        if (gy >= 0 && gy < 128 && gx >= 0 && gx < 128)
            v = *reinterpret_cast<const uint4*>(
                kvn + (((bb * 3 + f) * 128 + gy) * 128 + gx) * 64 + seg * 8);
        const unsigned short* pv = reinterpret_cast<const unsigned short*>(&v);
        #pragma unroll
        for (int j = 0; j < 8; ++j)
            kvpatch[f * 3072 + (seg * 8 + j) * 48 + hy * 8 + hx] = pv[j];
    }
    for (int u = tid; u < 288; u += 256) {
        int p = u >> 3, seg = u & 7;
        int hy = p / 6, hx = p - hy * 6;
        int gy = gy0 + hy, gx = gx0 + hx;
        uint4 v = make_uint4(0u, 0u, 0u, 0u);
        if (gy >= 0 && gy < 128 && gx >= 0 && gx < 128)
            v = *reinterpret_cast<const uint4*>(
                qn + ((bb * 128 + gy) * 128 + gx) * 64 + seg * 8);
        const unsigned short* pv = reinterpret_cast<const unsigned short*>(&v);
        #pragma unroll
        for (int j = 0; j < 8; ++j)
            qpatch[(seg * 8 + j) * 48 + hy * 8 + hx] = pv[j];
    }
    __syncthreads();

    // ---- q conv: 16 rows x 512 oc, scaled by 1/8, stored bf16 ----
    for (int it = 0; it < 4; ++it) {
        int task = it * 256 + tid;               // 0..1023
        int row = task & 15, ocg = task >> 4;    // ocg 0..63 (8 oc each)
        int y = row >> 2, x = row & 3;
        const unsigned short* pq = qpatch + y * 8 + x;
        const float* wb = wqp + ocg * 8;
        float acc[8] = {0.f,0.f,0.f,0.f,0.f,0.f,0.f,0.f};
        for (int ic = 0; ic < 64; ++ic) {
            #pragma unroll
            for (int tap = 0; tap < 9; ++tap) {
                const int ky = tap / 3, kx = tap - ky * 3;
                const float* wr = wb + (ic * 9 + tap) * 512;
                float4 w0 = *reinterpret_cast<const float4*>(wr);
                float4 w1 = *reinterpret_cast<const float4*>(wr + 4);
                float a = bs2f(pq[ic * 48 + ky * 8 + kx]);
                FMA8(a, w0, w1, acc);
            }
        }
        #pragma unroll
        for (int o = 0; o < 8; ++o)
            qls[row * 520 + ocg * 8 + o] = f2bs(0.125f * acc[o]);
    }
    __syncthreads();   // qpatch dead from here; kls region reused

    // ---- per-head: conv k,v -> attention -> ao ----
    const int row16 = tid >> 4;            // 0..15 (window row)
    const int ocg   = tid & 15;            // 0..7 k, 8..15 v
    const int isv   = ocg >> 3;
    const int oc8   = (ocg & 7) * 8;
    const int cy = row16 >> 2, cx = row16 & 3;
    const unsigned short* pk0 = kvpatch + cy * 8 + cx;

    const int qi = tid >> 4, qjg = tid & 15;       // QK phase roles
    const int pd = tid & 63, pig = tid >> 6;       // PV phase roles

    for (int h = 0; h < 8; ++h) {
        // conv k,v for this head: 48 rows x 8 oc per thread (3 frames)
        {
            const float* wb = wkvp + (isv ? 512 : 0) + h * 64 + oc8;
            float acc[3][8];
            #pragma unroll
            for (int f = 0; f < 3; ++f)
                #pragma unroll
                for (int o = 0; o < 8; ++o) acc[f][o] = 0.f;
            for (int ic = 0; ic < 64; ++ic) {
                #pragma unroll
                for (int tap = 0; tap < 9; ++tap) {
                    const int ky = tap / 3, kx = tap - ky * 3;
                    const float* wr = wb + (ic * 9 + tap) * 1024;
                    float4 w0 = *reinterpret_cast<const float4*>(wr);
                    float4 w1 = *reinterpret_cast<const float4*>(wr + 4);
                    const int poff = ic * 48 + ky * 8 + kx;
                    #pragma unroll
                    for (int f = 0; f < 3; ++f) {
                        float a = bs2f(pk0[f * 3072 + poff]);
                        FMA8(a, w0, w1, acc[f]);
                    }
                }
            }
            unsigned short* dst = isv ? vls : kls;
            #pragma unroll
            for (int f = 0; f < 3; ++f)
                #pragma unroll
                for (int o = 0; o < 8; ++o)
                    dst[(f * 16 + row16) * 72 + oc8 + o] = f2bs(acc[f][o]);
        }
        __syncthreads();

        // QK^T + softmax: thread (i=qi, jg=qjg) owns j = qjg+16t, t=0..2
        {
            const unsigned short* qrow = qls + qi * 520 + h * 64;
            float p[3];
            #pragma unroll
            for (int t = 0; t < 3; ++t) {
                int j = qjg + 16 * t;
                const unsigned short* krow = kls + j * 72;
                float s = 0.f;
                #pragma unroll
                for (int q8 = 0; q8 < 8; ++q8) {
                    uint4 ua = *reinterpret_cast<const uint4*>(qrow + q8 * 8);
                    uint4 ub = *reinterpret_cast<const uint4*>(krow + q8 * 8);
                    const unsigned short* pa = (const unsigned short*)&ua;
                    const unsigned short* pb = (const unsigned short*)&ub;
                    #pragma unroll
                    for (int o = 0; o < 8; ++o) s += bs2f(pa[o]) * bs2f(pb[o]);
                }
                p[t] = s + sa[(h * 16 + qi) * 48 + j];
            }
            float mx = fmaxf(p[0], fmaxf(p[1], p[2]));
            #pragma unroll
            for (int m = 1; m < 16; m <<= 1) mx = fmaxf(mx, __shfl_xor(mx, m));
            float sum = 0.f;
            #pragma unroll
            for (int t = 0; t < 3; ++t) { p[t] = __expf(p[t] - mx); sum += p[t]; }
            #pragma unroll
            for (int m = 1; m < 16; m <<= 1) sum += __shfl_xor(sum, m);
            float inv = 1.f / sum;
            #pragma unroll
            for (int t = 0; t < 3; ++t) atl[qi * 48 + qjg + 16 * t] = p[t] * inv;
        }
        __syncthreads();

        // PV: thread (d=pd, wave=pig) -> rows ii = pig*4+s
        {
            float acc[4] = {0.f, 0.f, 0.f, 0.f};
            for (int j = 0; j < 48; ++j) {
                float vj = bs2f(vls[j * 72 + pd]);
                #pragma unroll
                for (int s = 0; s < 4; ++s)
                    acc[s] += atl[(pig * 4 + s) * 48 + j] * vj;
            }
            #pragma unroll
            for (int s = 0; s < 4; ++s) {
                int ii = pig * 4 + s;
                int y = wy * 4 + (ii >> 2), x = wx * 4 + (ii & 3);
                ao[((bb * 128 + y) * 128 + x) * 512 + h * 64 + pd] = f2bs(acc[s]);
            }
        }
        __syncthreads();   // protect kls/vls/atl before next head overwrites
    }
}

// --------------------- 3x3 conv, IC=512 -> OC=64 (out conv) ----------------
// in ao (2,128,128,512) bf16 NHWC; out d_out (2,64,128,128) f32 NCHW.
__global__ __launch_bounds__(256) void conv512_kernel(
    const unsigned short* __restrict__ in,
    const float* __restrict__ wp,     // (4608, 64)
    float* __restrict__ out)
{
    __shared__ float patch[64][100];
    const int tid = threadIdx.x;
    const int tx = blockIdx.x & 15, ty = blockIdx.x >> 4;
    const int img = blockIdx.y;
    const int gx0 = tx * 8 - 1, gy0 = ty * 8 - 1;
    const int px = tid & 7, py = (tid >> 3) & 7, og = tid >> 6;

    float acc[16];
    #pragma unroll
    for (int o = 0; o < 16; ++o) acc[o] = 0.f;

    for (int ci = 0; ci < 8; ++ci) {
        __syncthreads();
        for (int u = tid; u < 100 * 8; u += 256) {
            int p = u >> 3, seg = u & 7;
            int hy = p / 10, hx = p - hy * 10;
            int gy = gy0 + hy, gx = gx0 + hx;
            uint4 v = make_uint4(0u, 0u, 0u, 0u);
            if (gy >= 0 && gy < 128 && gx >= 0 && gx < 128)
                v = *reinterpret_cast<const uint4*>(
                    in + ((img * 128 + gy) * 128 + gx) * 512 + ci * 64 + seg * 8);
            const unsigned short* pv = reinterpret_cast<const unsigned short*>(&v);
            #pragma unroll
            for (int j = 0; j < 8; ++j) patch[seg * 8 + j][p] = bs2f(pv[j]);
        }
        __syncthreads();
        for (int ic = 0; ic < 64; ++ic) {
            #pragma unroll
            for (int t = 0; t < 9; ++t) {
                const int ky = t / 3, kx = t - ky * 3;
                float a = patch[ic][(py + ky) * 10 + (px + kx)];
                const float* wr = wp + ((ci * 64 + ic) * 9 + t) * 64 + og * 16;
                float4 w0 = *reinterpret_cast<const float4*>(wr);
                float4 w1 = *reinterpret_cast<const float4*>(wr + 4);
                float4 w2 = *reinterpret_cast<const float4*>(wr + 8);
                float4 w3 = *reinterpret_cast<const float4*>(wr + 12);
                acc[0]  += a*w0.x; acc[1]  += a*w0.y; acc[2]  += a*w0.z; acc[3]  += a*w0.w;
                acc[4]  += a*w1.x; acc[5]  += a*w1.y; acc[6]  += a*w1.z; acc[7]  += a*w1.w;
                acc[8]  += a*w2.x; acc[9]  += a*w2.y; acc[10] += a*w2.z; acc[11] += a*w2.w;
                acc[12] += a*w3.x; acc[13] += a*w3.y; acc[14] += a*w3.z; acc[15] += a*w3.w;
            }
        }
    }
    const int gy = ty * 8 + py, gx = tx * 8 + px;
    #pragma unroll
    for (int o = 0; o < 16; ++o)
        out[((img * 64 + og * 16 + o) * 128 + gy) * 128 + gx] = acc[o];
}

// ---------------------------------------------------------------------------
extern "C" void kernel_launch(void* const* d_in, const int* in_sizes, int n_in,
                              void* d_out, int out_size, void* d_ws, size_t ws_size,
                              hipStream_t stream)
{
    const float* q_inp  = (const float*)d_in[0];
    const float* k_inp  = (const float*)d_in[1];
    const float* flow_f = (const float*)d_in[2];
    const float* flow_b = (const float*)d_in[3];
    const float* gq     = (const float*)d_in[4];
    const float* bq     = (const float*)d_in[5];
    const float* gkv    = (const float*)d_in[6];
    const float* bkv    = (const float*)d_in[7];
    const float* Wq     = (const float*)d_in[8];
    const float* Wkv    = (const float*)d_in[9];
    const float* Wout   = (const float*)d_in[10];
    const float* sa     = (const float*)d_in[11];

    if (ws_size < 55050240u) return;   // too-small ws -> clean absmax failure, not a crash

    char* ws = (char*)d_ws;
    unsigned short* qn  = (unsigned short*)(ws + 0);
    unsigned short* kvn = (unsigned short*)(ws + 4194304);
    unsigned short* ao  = (unsigned short*)(ws + 16777216);
    float*          wqp = (float*)         (ws + 50331648);
    float*          wkvp= (float*)         (ws + 51511296);
    float*          wop = (float*)         (ws + 53870592);

    ln_q_kernel<<<8192, 256, 0, stream>>>(q_inp, gq, bq, qn);
    warp_ln_kv_kernel<<<24576, 256, 0, stream>>>(k_inp, flow_f, flow_b, gkv, bkv, kvn);

    repack_kernel<<<(512 * 576 + 255) / 256, 256, 0, stream>>>(Wq, wqp, 512, 576);
    repack_kernel<<<(1024 * 576 + 255) / 256, 256, 0, stream>>>(Wkv, wkvp, 1024, 576);
    repack_kernel<<<(64 * 4608 + 255) / 256, 256, 0, stream>>>(Wout, wop, 64, 4608);

    fused_attn_kernel<<<dim3(1024, 2), 256, 0, stream>>>(qn, kvn, wqp, wkvp, sa, ao);

    conv512_kernel<<<dim3(256, 2), 256, 0, stream>>>(ao, wop, (float*)d_out);
}

// Round 3
// 645.249 us; speedup vs baseline: 6.7265x; 6.7265x over previous
//
#include <hip/hip_runtime.h>

// ---------------------------------------------------------------------------
// FGSW-MSA, round 3: MFMA bf16 implicit-GEMM convs + verified scalar attention.
// K-ordering for all convs: k = tap*64 + ic  (tap = ky*3+kx), so A-fragments
// are contiguous 16B reads from NHWC halo patches (no im2col).
//
// ws layout (bytes):
//   qn   (2,128,128,64)  bf16 @ 0           4,194,304
//   kvn  (6,128,128,64)  bf16 @ 4,194,304   12,582,912
//   ao   (2,128,128,512) bf16 @ 16,777,216  33,554,432
//   wq   (512,576)  bf16      @ 50,331,648    589,824
//   wkv  (1024,576) bf16      @ 50,921,472  1,179,648
//   wop  (64,4608)  bf16      @ 52,101,120    589,824
// total 52,690,944 B
// ---------------------------------------------------------------------------

typedef __attribute__((ext_vector_type(8))) short bf16x8;
typedef __attribute__((ext_vector_type(4))) float f32x4;

__device__ __forceinline__ float bs2f(unsigned short s) {
    return __uint_as_float(((unsigned int)s) << 16);
}
__device__ __forceinline__ unsigned short f2bs(float f) {
    unsigned int u = __float_as_uint(f);
    u += 0x7fffu + ((u >> 16) & 1u);   // RNE
    return (unsigned short)(u >> 16);
}

// ------------------------- LayerNorm (q path) ------------------------------
__global__ __launch_bounds__(256) void ln_q_kernel(
    const float* __restrict__ q_inp, const float* __restrict__ g,
    const float* __restrict__ b, unsigned short* __restrict__ qn)
{
    int wid  = (blockIdx.x * 256 + threadIdx.x) >> 6;
    int lane = threadIdx.x & 63;
    int pix  = wid & 16383;
    int bb   = wid >> 14;
    float val = q_inp[(bb * 64 + lane) * 16384 + pix];
    float s = val;
    #pragma unroll
    for (int m = 1; m < 64; m <<= 1) s += __shfl_xor(s, m);
    float mu = s * (1.f / 64.f);
    float d = val - mu;
    float s2 = d * d;
    #pragma unroll
    for (int m = 1; m < 64; m <<= 1) s2 += __shfl_xor(s2, m);
    float o = d * rsqrtf(s2 * (1.f / 64.f) + 1e-5f) * g[lane] + b[lane];
    qn[wid * 64 + lane] = f2bs(o);
}

// --------------------- nearest-warp + LayerNorm (kv path) ------------------
__global__ __launch_bounds__(256) void warp_ln_kv_kernel(
    const float* __restrict__ k_inp, const float* __restrict__ flow_f,
    const float* __restrict__ flow_b, const float* __restrict__ g,
    const float* __restrict__ b, unsigned short* __restrict__ kvn)
{
    int wid  = (blockIdx.x * 256 + threadIdx.x) >> 6;
    int lane = threadIdx.x & 63;
    int x  = wid & 127;
    int y  = (wid >> 7) & 127;
    int bf = wid >> 14;
    int f  = bf % 3, bb = bf / 3;
    float val;
    if (f == 1) {
        val = k_inp[(bf * 64 + lane) * 16384 + y * 128 + x];
    } else {
        const float* fl = (f == 0) ? flow_f : flow_b;
        float fx = fl[(bb * 2 + 0) * 16384 + y * 128 + x];
        float fy = fl[(bb * 2 + 1) * 16384 + y * 128 + x];
        int ix = (int)rintf((float)x + fx);
        int iy = (int)rintf((float)y + fy);
        if (ix >= 0 && ix < 128 && iy >= 0 && iy < 128)
            val = k_inp[(bf * 64 + lane) * 16384 + iy * 128 + ix];
        else
            val = 0.f;
    }
    float s = val;
    #pragma unroll
    for (int m = 1; m < 64; m <<= 1) s += __shfl_xor(s, m);
    float mu = s * (1.f / 64.f);
    float d = val - mu;
    float s2 = d * d;
    #pragma unroll
    for (int m = 1; m < 64; m <<= 1) s2 += __shfl_xor(s2, m);
    float o = d * rsqrtf(s2 * (1.f / 64.f) + 1e-5f) * g[lane] + b[lane];
    kvn[wid * 64 + lane] = f2bs(o);
}

// --------------------------- weight repack (f32 -> bf16) --------------------
// src (OC, IC, 3, 3); dst[oc][ (ic/64)*576 + tap*64 + (ic%64) ]
__global__ __launch_bounds__(256) void repack_bf16_kernel(
    const float* __restrict__ w, unsigned short* __restrict__ wp,
    int IC, int total)
{
    int idx = blockIdx.x * 256 + threadIdx.x;
    if (idx >= total) return;
    int tap = idx % 9;
    int tmp = idx / 9;
    int ic  = tmp % IC;
    int oc  = tmp / IC;
    wp[oc * IC * 9 + (ic >> 6) * 576 + tap * 64 + (ic & 63)] = f2bs(w[idx]);
}

// ----------------- fused conv_q + conv_kv + window attention ---------------
// grid (1024, 2). 256 thr = 4 waves.
// LDS (49,088 B):
//   kvp  u16[3][36][72] @ 0      (15,552)  NHWC halo patches, pos = hy*6+hx
//   qls  u16[16][520]   @ 15,552 (16,640)  q conv out (scaled 1/8), bf16
//   kls  u16[48][72]    @ 32,192 ( 6,912)  per-head k   (qpatch union)
//   vls  u16[48][72]    @ 39,104 ( 6,912)  per-head v
//   atl  f32[16][48]    @ 46,016 ( 3,072)
__global__ __launch_bounds__(256) void fused_attn_kernel(
    const unsigned short* __restrict__ qn,
    const unsigned short* __restrict__ kvn,
    const unsigned short* __restrict__ wq,
    const unsigned short* __restrict__ wkv,
    const float* __restrict__ sa,
    unsigned short* __restrict__ ao)
{
    __shared__ __align__(16) unsigned char smem[49088];
    unsigned short* kvp = (unsigned short*)smem;
    unsigned short* qls = (unsigned short*)(smem + 15552);
    unsigned short* kls = (unsigned short*)(smem + 32192);
    unsigned short* vls = (unsigned short*)(smem + 39104);
    float*          atl = (float*)(smem + 46016);
    unsigned short* qpatch = kls;   // [36][72], dead before head loop

    const int tid  = threadIdx.x;
    const int lane = tid & 63;
    const int w    = tid >> 6;
    const int wx = blockIdx.x & 31, wy = blockIdx.x >> 5;
    const int bb = blockIdx.y;
    const int gx0 = wx * 4 - 1, gy0 = wy * 4 - 1;

    // ---- stage kv halo patches (NHWC, row padded to 72 ch) ----
    for (int u = tid; u < 864; u += 256) {
        int f = u / 288, rest = u - f * 288;
        int pos = rest >> 3, seg = rest & 7;
        int hy = pos / 6, hx = pos - hy * 6;
        int gy = gy0 + hy, gx = gx0 + hx;
        uint4 v = make_uint4(0u, 0u, 0u, 0u);
        if ((unsigned)gy < 128u && (unsigned)gx < 128u)
            v = *reinterpret_cast<const uint4*>(
                kvn + (((bb * 3 + f) * 128 + gy) * 128 + gx) * 64 + seg * 8);
        *reinterpret_cast<uint4*>(kvp + (f * 36 + pos) * 72 + seg * 8) = v;
    }
    // ---- stage q halo patch ----
    for (int u = tid; u < 288; u += 256) {
        int pos = u >> 3, seg = u & 7;
        int hy = pos / 6, hx = pos - hy * 6;
        int gy = gy0 + hy, gx = gx0 + hx;
        uint4 v = make_uint4(0u, 0u, 0u, 0u);
        if ((unsigned)gy < 128u && (unsigned)gx < 128u)
            v = *reinterpret_cast<const uint4*>(
                qn + ((bb * 128 + gy) * 128 + gx) * 64 + seg * 8);
        *reinterpret_cast<uint4*>(qpatch + pos * 72 + seg * 8) = v;
    }
    __syncthreads();

    const int r  = lane & 15;      // MFMA: A-row / B-col within tile
    const int kg = lane >> 4;      // MFMA: k-group (8 elems each)
    const int py = r >> 2, px = r & 3;

    // ---- q conv: M=16 px, N=512, K=576.  wave w owns oc tiles w*8..w*8+7 ----
    for (int g = 0; g < 2; ++g) {
        f32x4 acc0 = {0.f,0.f,0.f,0.f}, acc1 = acc0, acc2 = acc0, acc3 = acc0;
        #pragma unroll 3
        for (int kk = 0; kk < 18; ++kk) {
            int tap = kk >> 1, ic0 = (kk & 1) * 32;
            int ky = tap / 3, kx = tap - ky * 3;
            int pos = (py + ky) * 6 + (px + kx);
            bf16x8 a = *reinterpret_cast<const bf16x8*>(qpatch + pos * 72 + ic0 + kg * 8);
            const unsigned short* wb = wq + (w * 8 + g * 4) * 16 * 576 + kk * 32 + kg * 8;
            bf16x8 b0 = *reinterpret_cast<const bf16x8*>(wb + (0 * 16 + r) * 576);
            bf16x8 b1 = *reinterpret_cast<const bf16x8*>(wb + (1 * 16 + r) * 576);
            bf16x8 b2 = *reinterpret_cast<const bf16x8*>(wb + (2 * 16 + r) * 576);
            bf16x8 b3 = *reinterpret_cast<const bf16x8*>(wb + (3 * 16 + r) * 576);
            acc0 = __builtin_amdgcn_mfma_f32_16x16x32_bf16(a, b0, acc0, 0, 0, 0);
            acc1 = __builtin_amdgcn_mfma_f32_16x16x32_bf16(a, b1, acc1, 0, 0, 0);
            acc2 = __builtin_amdgcn_mfma_f32_16x16x32_bf16(a, b2, acc2, 0, 0, 0);
            acc3 = __builtin_amdgcn_mfma_f32_16x16x32_bf16(a, b3, acc3, 0, 0, 0);
        }
        #pragma unroll
        for (int reg = 0; reg < 4; ++reg) {
            int row = kg * 4 + reg;
            int cb  = (w * 8 + g * 4) * 16 + r;
            qls[row * 520 + cb +  0] = f2bs(0.125f * acc0[reg]);
            qls[row * 520 + cb + 16] = f2bs(0.125f * acc1[reg]);
            qls[row * 520 + cb + 32] = f2bs(0.125f * acc2[reg]);
            qls[row * 520 + cb + 48] = f2bs(0.125f * acc3[reg]);
        }
    }
    __syncthreads();   // qls complete; qpatch region becomes kls

    // ---- per-head loop ----
    const int is_v = w >> 1, pair = w & 1;
    const int qi = tid >> 4, qjg = tid & 15;       // QK roles
    const int pd = tid & 63, pig = tid >> 6;       // PV roles

    for (int h = 0; h < 8; ++h) {
        // conv k,v for this head: M=48 (3 frames x 16 px), wave owns 2 oc-tiles
        {
            f32x4 c00 = {0.f,0.f,0.f,0.f}, c01 = c00, c10 = c00, c11 = c00, c20 = c00, c21 = c00;
            #pragma unroll 3
            for (int kk = 0; kk < 18; ++kk) {
                int tap = kk >> 1, ic0 = (kk & 1) * 32;
                int ky = tap / 3, kx = tap - ky * 3;
                int pos = (py + ky) * 6 + (px + kx);
                bf16x8 a0 = *reinterpret_cast<const bf16x8*>(kvp + pos * 72 + ic0 + kg * 8);
                bf16x8 a1 = *reinterpret_cast<const bf16x8*>(kvp + (36 + pos) * 72 + ic0 + kg * 8);
                bf16x8 a2 = *reinterpret_cast<const bf16x8*>(kvp + (72 + pos) * 72 + ic0 + kg * 8);
                int ocb = is_v * 512 + h * 64 + pair * 32;
                const unsigned short* wb = wkv + (size_t)ocb * 576 + kk * 32 + kg * 8;
                bf16x8 b0 = *reinterpret_cast<const bf16x8*>(wb + (size_t)(r) * 576);
                bf16x8 b1 = *reinterpret_cast<const bf16x8*>(wb + (size_t)(16 + r) * 576);
                c00 = __builtin_amdgcn_mfma_f32_16x16x32_bf16(a0, b0, c00, 0, 0, 0);
                c10 = __builtin_amdgcn_mfma_f32_16x16x32_bf16(a1, b0, c10, 0, 0, 0);
                c20 = __builtin_amdgcn_mfma_f32_16x16x32_bf16(a2, b0, c20, 0, 0, 0);
                c01 = __builtin_amdgcn_mfma_f32_16x16x32_bf16(a0, b1, c01, 0, 0, 0);
                c11 = __builtin_amdgcn_mfma_f32_16x16x32_bf16(a1, b1, c11, 0, 0, 0);
                c21 = __builtin_amdgcn_mfma_f32_16x16x32_bf16(a2, b1, c21, 0, 0, 0);
            }
            unsigned short* dst = is_v ? vls : kls;
            #pragma unroll
            for (int reg = 0; reg < 4; ++reg) {
                int jr = kg * 4 + reg;
                int cb = pair * 32 + r;
                dst[(jr +  0) * 72 + cb]      = f2bs(c00[reg]);
                dst[(jr + 16) * 72 + cb]      = f2bs(c10[reg]);
                dst[(jr + 32) * 72 + cb]      = f2bs(c20[reg]);
                dst[(jr +  0) * 72 + cb + 16] = f2bs(c01[reg]);
                dst[(jr + 16) * 72 + cb + 16] = f2bs(c11[reg]);
                dst[(jr + 32) * 72 + cb + 16] = f2bs(c21[reg]);
            }
        }
        __syncthreads();

        // QK^T + softmax (scalar, verified round 2)
        {
            const unsigned short* qrow = qls + qi * 520 + h * 64;
            float p[3];
            #pragma unroll
            for (int t = 0; t < 3; ++t) {
                int j = qjg + 16 * t;
                const unsigned short* krow = kls + j * 72;
                float s = 0.f;
                #pragma unroll
                for (int q8 = 0; q8 < 8; ++q8) {
                    uint4 ua = *reinterpret_cast<const uint4*>(qrow + q8 * 8);
                    uint4 ub = *reinterpret_cast<const uint4*>(krow + q8 * 8);
                    const unsigned short* pa = (const unsigned short*)&ua;
                    const unsigned short* pb = (const unsigned short*)&ub;
                    #pragma unroll
                    for (int o = 0; o < 8; ++o) s += bs2f(pa[o]) * bs2f(pb[o]);
                }
                p[t] = s + sa[(h * 16 + qi) * 48 + j];
            }
            float mx = fmaxf(p[0], fmaxf(p[1], p[2]));
            #pragma unroll
            for (int m = 1; m < 16; m <<= 1) mx = fmaxf(mx, __shfl_xor(mx, m));
            float sum = 0.f;
            #pragma unroll
            for (int t = 0; t < 3; ++t) { p[t] = __expf(p[t] - mx); sum += p[t]; }
            #pragma unroll
            for (int m = 1; m < 16; m <<= 1) sum += __shfl_xor(sum, m);
            float inv = 1.f / sum;
            #pragma unroll
            for (int t = 0; t < 3; ++t) atl[qi * 48 + qjg + 16 * t] = p[t] * inv;
        }
        __syncthreads();

        // PV (scalar, verified round 2)
        {
            float acc[4] = {0.f, 0.f, 0.f, 0.f};
            for (int j = 0; j < 48; ++j) {
                float vj = bs2f(vls[j * 72 + pd]);
                #pragma unroll
                for (int s = 0; s < 4; ++s)
                    acc[s] += atl[(pig * 4 + s) * 48 + j] * vj;
            }
            #pragma unroll
            for (int s = 0; s < 4; ++s) {
                int ii = pig * 4 + s;
                int y = wy * 4 + (ii >> 2), x = wx * 4 + (ii & 3);
                ao[((bb * 128 + y) * 128 + x) * 512 + h * 64 + pd] = f2bs(acc[s]);
            }
        }
        __syncthreads();
    }
}

// --------------- 3x3 conv, IC=512 -> OC=64 via MFMA (out conv) -------------
// in ao (2,128,128,512) bf16 NHWC; out (2,64,128,128) f32 NCHW.
// block = 64 px (8x8), 4 waves; wave w = oc-tile w; IC chunked 8x64.
__global__ __launch_bounds__(256) void conv512_kernel(
    const unsigned short* __restrict__ in,
    const unsigned short* __restrict__ wp,    // (64, 4608) bf16
    float* __restrict__ out)
{
    __shared__ __align__(16) unsigned short patch[100 * 72];
    const int tid = threadIdx.x, lane = tid & 63, w = tid >> 6;
    const int tx = blockIdx.x & 15, ty = blockIdx.x >> 4;
    const int img = blockIdx.y;
    const int gx0 = tx * 8 - 1, gy0 = ty * 8 - 1;
    const int r = lane & 15, kg = lane >> 4;

    f32x4 acc0 = {0.f,0.f,0.f,0.f}, acc1 = acc0, acc2 = acc0, acc3 = acc0;

    for (int ci = 0; ci < 8; ++ci) {
        __syncthreads();
        for (int u = tid; u < 800; u += 256) {
            int pos = u >> 3, seg = u & 7;
            int hy = pos / 10, hx = pos - hy * 10;
            int gy = gy0 + hy, gx = gx0 + hx;
            uint4 v = make_uint4(0u, 0u, 0u, 0u);
            if ((unsigned)gy < 128u && (unsigned)gx < 128u)
                v = *reinterpret_cast<const uint4*>(
                    in + (((size_t)img * 128 + gy) * 128 + gx) * 512 + ci * 64 + seg * 8);
            *reinterpret_cast<uint4*>(patch + pos * 72 + seg * 8) = v;
        }
        __syncthreads();
        #pragma unroll 3
        for (int kk = 0; kk < 18; ++kk) {
            int tap = kk >> 1, ic0 = (kk & 1) * 32;
            int ky = tap / 3, kx = tap - ky * 3;
            int oc = w * 16 + r;
            bf16x8 b = *reinterpret_cast<const bf16x8*>(
                wp + (size_t)oc * 4608 + ci * 576 + kk * 32 + kg * 8);
            #pragma unroll
            for (int m = 0; m < 4; ++m) {
                int rr = m * 16 + r;
                int pos = ((rr >> 3) + ky) * 10 + (rr & 7) + kx;
                bf16x8 a = *reinterpret_cast<const bf16x8*>(patch + pos * 72 + ic0 + kg * 8);
                f32x4& acc = (m == 0) ? acc0 : (m == 1) ? acc1 : (m == 2) ? acc2 : acc3;
                acc = __builtin_amdgcn_mfma_f32_16x16x32_bf16(a, b, acc, 0, 0, 0);
            }
        }
    }
    const int oc = w * 16 + r;
    #pragma unroll
    for (int m = 0; m < 4; ++m) {
        const f32x4& acc = (m == 0) ? acc0 : (m == 1) ? acc1 : (m == 2) ? acc2 : acc3;
        int r0 = m * 16 + kg * 4;
        int gy = ty * 8 + (r0 >> 3), gx = tx * 8 + (r0 & 7);
        *reinterpret_cast<float4*>(
            out + (((size_t)img * 64 + oc) * 128 + gy) * 128 + gx) =
            make_float4(acc[0], acc[1], acc[2], acc[3]);
    }
}

// ---------------------------------------------------------------------------
extern "C" void kernel_launch(void* const* d_in, const int* in_sizes, int n_in,
                              void* d_out, int out_size, void* d_ws, size_t ws_size,
                              hipStream_t stream)
{
    const float* q_inp  = (const float*)d_in[0];
    const float* k_inp  = (const float*)d_in[1];
    const float* flow_f = (const float*)d_in[2];
    const float* flow_b = (const float*)d_in[3];
    const float* gq     = (const float*)d_in[4];
    const float* bq     = (const float*)d_in[5];
    const float* gkv    = (const float*)d_in[6];
    const float* bkv    = (const float*)d_in[7];
    const float* Wq     = (const float*)d_in[8];
    const float* Wkv    = (const float*)d_in[9];
    const float* Wout   = (const float*)d_in[10];
    const float* sa     = (const float*)d_in[11];

    if (ws_size < 55050240u) return;

    char* ws = (char*)d_ws;
    unsigned short* qn   = (unsigned short*)(ws + 0);
    unsigned short* kvn  = (unsigned short*)(ws + 4194304);
    unsigned short* ao   = (unsigned short*)(ws + 16777216);
    unsigned short* wqb  = (unsigned short*)(ws + 50331648);
    unsigned short* wkvb = (unsigned short*)(ws + 50921472);
    unsigned short* wopb = (unsigned short*)(ws + 52101120);

    ln_q_kernel<<<8192, 256, 0, stream>>>(q_inp, gq, bq, qn);
    warp_ln_kv_kernel<<<24576, 256, 0, stream>>>(k_inp, flow_f, flow_b, gkv, bkv, kvn);

    repack_bf16_kernel<<<1152, 256, 0, stream>>>(Wq,   wqb,  64,  294912);
    repack_bf16_kernel<<<2304, 256, 0, stream>>>(Wkv,  wkvb, 64,  589824);
    repack_bf16_kernel<<<1152, 256, 0, stream>>>(Wout, wopb, 512, 294912);

    fused_attn_kernel<<<dim3(1024, 2), 256, 0, stream>>>(qn, kvn, wqb, wkvb, sa, ao);

    conv512_kernel<<<dim3(256, 2), 256, 0, stream>>>(ao, wopb, (float*)d_out);
}

// Round 4
// 606.780 us; speedup vs baseline: 7.1530x; 1.0634x over previous
//
#include <hip/hip_runtime.h>

// ---------------------------------------------------------------------------
// FGSW-MSA, round 4: everything matmul-shaped on MFMA (convs + QK^T + PV).
// Fragment conventions (verified by passing round 3):
//   A: lane row = l&15, k = (l>>4)*8+j  (contiguous b128)
//   B: lane col = l&15, k = (l>>4)*8+j  (contiguous b128 of row-major [n][k])
//   C: row = (l>>4)*4+reg, col = l&15
//
// ws layout (bytes):
//   qn   (2,128,128,64)  bf16 @ 0           4,194,304
//   kvn  (6,128,128,64)  bf16 @ 4,194,304   12,582,912
//   ao   (2,128,128,512) bf16 @ 16,777,216  33,554,432
//   wq   (512,576)  bf16      @ 50,331,648    589,824
//   wkv  (1024,576) bf16      @ 50,921,472  1,179,648
//   wop  (64,4608)  bf16      @ 52,101,120    589,824
// ---------------------------------------------------------------------------

typedef __attribute__((ext_vector_type(8))) short bf16x8;
typedef __attribute__((ext_vector_type(4))) float f32x4;

__device__ __forceinline__ float bs2f(unsigned short s) {
    return __uint_as_float(((unsigned int)s) << 16);
}
__device__ __forceinline__ unsigned short f2bs(float f) {
    unsigned int u = __float_as_uint(f);
    u += 0x7fffu + ((u >> 16) & 1u);   // RNE
    return (unsigned short)(u >> 16);
}

// ------------------------- LayerNorm (q path) ------------------------------
__global__ __launch_bounds__(256) void ln_q_kernel(
    const float* __restrict__ q_inp, const float* __restrict__ g,
    const float* __restrict__ b, unsigned short* __restrict__ qn)
{
    int wid  = (blockIdx.x * 256 + threadIdx.x) >> 6;
    int lane = threadIdx.x & 63;
    int pix  = wid & 16383;
    int bb   = wid >> 14;
    float val = q_inp[(bb * 64 + lane) * 16384 + pix];
    float s = val;
    #pragma unroll
    for (int m = 1; m < 64; m <<= 1) s += __shfl_xor(s, m);
    float mu = s * (1.f / 64.f);
    float d = val - mu;
    float s2 = d * d;
    #pragma unroll
    for (int m = 1; m < 64; m <<= 1) s2 += __shfl_xor(s2, m);
    float o = d * rsqrtf(s2 * (1.f / 64.f) + 1e-5f) * g[lane] + b[lane];
    qn[wid * 64 + lane] = f2bs(o);
}

// --------------------- nearest-warp + LayerNorm (kv path) ------------------
__global__ __launch_bounds__(256) void warp_ln_kv_kernel(
    const float* __restrict__ k_inp, const float* __restrict__ flow_f,
    const float* __restrict__ flow_b, const float* __restrict__ g,
    const float* __restrict__ b, unsigned short* __restrict__ kvn)
{
    int wid  = (blockIdx.x * 256 + threadIdx.x) >> 6;
    int lane = threadIdx.x & 63;
    int x  = wid & 127;
    int y  = (wid >> 7) & 127;
    int bf = wid >> 14;
    int f  = bf % 3, bb = bf / 3;
    float val;
    if (f == 1) {
        val = k_inp[(bf * 64 + lane) * 16384 + y * 128 + x];
    } else {
        const float* fl = (f == 0) ? flow_f : flow_b;
        float fx = fl[(bb * 2 + 0) * 16384 + y * 128 + x];
        float fy = fl[(bb * 2 + 1) * 16384 + y * 128 + x];
        int ix = (int)rintf((float)x + fx);
        int iy = (int)rintf((float)y + fy);
        if (ix >= 0 && ix < 128 && iy >= 0 && iy < 128)
            val = k_inp[(bf * 64 + lane) * 16384 + iy * 128 + ix];
        else
            val = 0.f;
    }
    float s = val;
    #pragma unroll
    for (int m = 1; m < 64; m <<= 1) s += __shfl_xor(s, m);
    float mu = s * (1.f / 64.f);
    float d = val - mu;
    float s2 = d * d;
    #pragma unroll
    for (int m = 1; m < 64; m <<= 1) s2 += __shfl_xor(s2, m);
    float o = d * rsqrtf(s2 * (1.f / 64.f) + 1e-5f) * g[lane] + b[lane];
    kvn[wid * 64 + lane] = f2bs(o);
}

// --------------------------- weight repack (f32 -> bf16) --------------------
// src (OC, IC, 3, 3); dst[oc][ (ic/64)*576 + tap*64 + (ic%64) ]
__global__ __launch_bounds__(256) void repack_bf16_kernel(
    const float* __restrict__ w, unsigned short* __restrict__ wp,
    int IC, int total)
{
    int idx = blockIdx.x * 256 + threadIdx.x;
    if (idx >= total) return;
    int tap = idx % 9;
    int tmp = idx / 9;
    int ic  = tmp % IC;
    int oc  = tmp / IC;
    wp[oc * IC * 9 + (ic >> 6) * 576 + tap * 64 + (ic & 63)] = f2bs(w[idx]);
}

// ----------------- fused conv_q + conv_kv + window attention ---------------
// grid (1024, 2). 256 thr = 4 waves.
// LDS (50,624 B):
//   kvp   u16[3][36][72] @ 0      (15,552)  NHWC halo patches
//   qls   u16[16][520]   @ 15,552 (16,640)  q conv out (x 1/8), bf16
//   kls   u16[48][72]    @ 32,192 ( 6,912)  per-head k, row-major  (qpatch union)
//   vls_T u16[64][72]    @ 39,104 ( 9,216)  per-head v, TRANSPOSED [d][j], j pad 48..63 = 0
//   pls   u16[16][72]    @ 48,320 ( 2,304)  S then P, bf16, cols 48..63 = 0
__global__ __launch_bounds__(256) void fused_attn_kernel(
    const unsigned short* __restrict__ qn,
    const unsigned short* __restrict__ kvn,
    const unsigned short* __restrict__ wq,
    const unsigned short* __restrict__ wkv,
    const float* __restrict__ sa,
    unsigned short* __restrict__ ao)
{
    __shared__ __align__(16) unsigned char smem[50624];
    unsigned short* kvp   = (unsigned short*)smem;
    unsigned short* qls   = (unsigned short*)(smem + 15552);
    unsigned short* kls   = (unsigned short*)(smem + 32192);
    unsigned short* vls_T = (unsigned short*)(smem + 39104);
    unsigned short* pls   = (unsigned short*)(smem + 48320);
    unsigned short* qpatch = kls;   // [36][72], dead before head loop

    const int tid  = threadIdx.x;
    const int lane = tid & 63;
    const int w    = tid >> 6;
    const int wx = blockIdx.x & 31, wy = blockIdx.x >> 5;
    const int bb = blockIdx.y;
    const int gx0 = wx * 4 - 1, gy0 = wy * 4 - 1;

    // ---- stage kv halo patches ----
    for (int u = tid; u < 864; u += 256) {
        int f = u / 288, rest = u - f * 288;
        int pos = rest >> 3, seg = rest & 7;
        int hy = pos / 6, hx = pos - hy * 6;
        int gy = gy0 + hy, gx = gx0 + hx;
        uint4 v = make_uint4(0u, 0u, 0u, 0u);
        if ((unsigned)gy < 128u && (unsigned)gx < 128u)
            v = *reinterpret_cast<const uint4*>(
                kvn + (((bb * 3 + f) * 128 + gy) * 128 + gx) * 64 + seg * 8);
        *reinterpret_cast<uint4*>(kvp + (f * 36 + pos) * 72 + seg * 8) = v;
    }
    // ---- stage q halo patch ----
    for (int u = tid; u < 288; u += 256) {
        int pos = u >> 3, seg = u & 7;
        int hy = pos / 6, hx = pos - hy * 6;
        int gy = gy0 + hy, gx = gx0 + hx;
        uint4 v = make_uint4(0u, 0u, 0u, 0u);
        if ((unsigned)gy < 128u && (unsigned)gx < 128u)
            v = *reinterpret_cast<const uint4*>(
                qn + ((bb * 128 + gy) * 128 + gx) * 64 + seg * 8);
        *reinterpret_cast<uint4*>(qpatch + pos * 72 + seg * 8) = v;
    }
    // ---- one-time zero pads (j = 48..63) for K=48->64 padding ----
    for (int u = tid; u < 1024; u += 256) {        // vls_T
        int row = u >> 4, c = 48 + (u & 15);
        vls_T[row * 72 + c] = 0;
    }
    if (tid < 256) {                               // pls (16x16)
        int row = tid >> 4, c = 48 + (tid & 15);
        pls[row * 72 + c] = 0;
    }
    __syncthreads();

    const int r  = lane & 15;
    const int kg = lane >> 4;
    const int py = r >> 2, px = r & 3;

    // ---- q conv: M=16 px, N=512, K=576 ----
    for (int g = 0; g < 2; ++g) {
        f32x4 acc0 = {0.f,0.f,0.f,0.f}, acc1 = acc0, acc2 = acc0, acc3 = acc0;
        #pragma unroll 3
        for (int kk = 0; kk < 18; ++kk) {
            int tap = kk >> 1, ic0 = (kk & 1) * 32;
            int ky = tap / 3, kx = tap - ky * 3;
            int pos = (py + ky) * 6 + (px + kx);
            bf16x8 a = *reinterpret_cast<const bf16x8*>(qpatch + pos * 72 + ic0 + kg * 8);
            const unsigned short* wb = wq + (w * 8 + g * 4) * 16 * 576 + kk * 32 + kg * 8;
            bf16x8 b0 = *reinterpret_cast<const bf16x8*>(wb + (0 * 16 + r) * 576);
            bf16x8 b1 = *reinterpret_cast<const bf16x8*>(wb + (1 * 16 + r) * 576);
            bf16x8 b2 = *reinterpret_cast<const bf16x8*>(wb + (2 * 16 + r) * 576);
            bf16x8 b3 = *reinterpret_cast<const bf16x8*>(wb + (3 * 16 + r) * 576);
            acc0 = __builtin_amdgcn_mfma_f32_16x16x32_bf16(a, b0, acc0, 0, 0, 0);
            acc1 = __builtin_amdgcn_mfma_f32_16x16x32_bf16(a, b1, acc1, 0, 0, 0);
            acc2 = __builtin_amdgcn_mfma_f32_16x16x32_bf16(a, b2, acc2, 0, 0, 0);
            acc3 = __builtin_amdgcn_mfma_f32_16x16x32_bf16(a, b3, acc3, 0, 0, 0);
        }
        #pragma unroll
        for (int reg = 0; reg < 4; ++reg) {
            int row = kg * 4 + reg;
            int cb  = (w * 8 + g * 4) * 16 + r;
            qls[row * 520 + cb +  0] = f2bs(0.125f * acc0[reg]);
            qls[row * 520 + cb + 16] = f2bs(0.125f * acc1[reg]);
            qls[row * 520 + cb + 32] = f2bs(0.125f * acc2[reg]);
            qls[row * 520 + cb + 48] = f2bs(0.125f * acc3[reg]);
        }
    }
    __syncthreads();   // qls complete; qpatch region becomes kls

    const int is_v = w >> 1, pair = w & 1;
    const int si = tid >> 4, sjg = tid & 15;   // softmax roles

    for (int h = 0; h < 8; ++h) {
        // ---- conv k,v for this head (k row-major; v transposed) ----
        {
            f32x4 c00 = {0.f,0.f,0.f,0.f}, c01 = c00, c10 = c00, c11 = c00, c20 = c00, c21 = c00;
            #pragma unroll 3
            for (int kk = 0; kk < 18; ++kk) {
                int tap = kk >> 1, ic0 = (kk & 1) * 32;
                int ky = tap / 3, kx = tap - ky * 3;
                int pos = (py + ky) * 6 + (px + kx);
                bf16x8 a0 = *reinterpret_cast<const bf16x8*>(kvp + pos * 72 + ic0 + kg * 8);
                bf16x8 a1 = *reinterpret_cast<const bf16x8*>(kvp + (36 + pos) * 72 + ic0 + kg * 8);
                bf16x8 a2 = *reinterpret_cast<const bf16x8*>(kvp + (72 + pos) * 72 + ic0 + kg * 8);
                int ocb = is_v * 512 + h * 64 + pair * 32;
                const unsigned short* wb = wkv + (size_t)ocb * 576 + kk * 32 + kg * 8;
                bf16x8 b0 = *reinterpret_cast<const bf16x8*>(wb + (size_t)(r) * 576);
                bf16x8 b1 = *reinterpret_cast<const bf16x8*>(wb + (size_t)(16 + r) * 576);
                c00 = __builtin_amdgcn_mfma_f32_16x16x32_bf16(a0, b0, c00, 0, 0, 0);
                c10 = __builtin_amdgcn_mfma_f32_16x16x32_bf16(a1, b0, c10, 0, 0, 0);
                c20 = __builtin_amdgcn_mfma_f32_16x16x32_bf16(a2, b0, c20, 0, 0, 0);
                c01 = __builtin_amdgcn_mfma_f32_16x16x32_bf16(a0, b1, c01, 0, 0, 0);
                c11 = __builtin_amdgcn_mfma_f32_16x16x32_bf16(a1, b1, c11, 0, 0, 0);
                c21 = __builtin_amdgcn_mfma_f32_16x16x32_bf16(a2, b1, c21, 0, 0, 0);
            }
            if (!is_v) {
                // k: kls[j][ch], j = frame*16 + kg*4+reg, ch = pair*32 + (0|16) + r
                #pragma unroll
                for (int reg = 0; reg < 4; ++reg) {
                    int jr = kg * 4 + reg;
                    int cb = pair * 32 + r;
                    kls[(jr +  0) * 72 + cb]      = f2bs(c00[reg]);
                    kls[(jr + 16) * 72 + cb]      = f2bs(c10[reg]);
                    kls[(jr + 32) * 72 + cb]      = f2bs(c20[reg]);
                    kls[(jr +  0) * 72 + cb + 16] = f2bs(c01[reg]);
                    kls[(jr + 16) * 72 + cb + 16] = f2bs(c11[reg]);
                    kls[(jr + 32) * 72 + cb + 16] = f2bs(c21[reg]);
                }
            } else {
                // v transposed: vls_T[d][j], d = pair*32 + (0|16) + r, j = frame*16 + kg*4+reg
                #pragma unroll
                for (int reg = 0; reg < 4; ++reg) {
                    int jr = kg * 4 + reg;
                    int d0 = pair * 32 + r;
                    vls_T[d0 * 72        + jr]      = f2bs(c00[reg]);
                    vls_T[d0 * 72        + 16 + jr] = f2bs(c10[reg]);
                    vls_T[d0 * 72        + 32 + jr] = f2bs(c20[reg]);
                    vls_T[(d0 + 16) * 72 + jr]      = f2bs(c01[reg]);
                    vls_T[(d0 + 16) * 72 + 16 + jr] = f2bs(c11[reg]);
                    vls_T[(d0 + 16) * 72 + 32 + jr] = f2bs(c21[reg]);
                }
            }
        }
        __syncthreads();

        // ---- QK^T via MFMA: waves 0..2, tile w: cols j = w*16 + r ----
        if (w < 3) {
            f32x4 s_acc = {0.f, 0.f, 0.f, 0.f};
            #pragma unroll
            for (int s = 0; s < 2; ++s) {
                bf16x8 a = *reinterpret_cast<const bf16x8*>(
                    qls + r * 520 + h * 64 + s * 32 + kg * 8);
                bf16x8 b = *reinterpret_cast<const bf16x8*>(
                    kls + (w * 16 + r) * 72 + s * 32 + kg * 8);
                s_acc = __builtin_amdgcn_mfma_f32_16x16x32_bf16(a, b, s_acc, 0, 0, 0);
            }
            #pragma unroll
            for (int reg = 0; reg < 4; ++reg) {
                int i = kg * 4 + reg, j = w * 16 + r;
                float val = s_acc[reg] + sa[(h * 16 + i) * 48 + j];
                pls[i * 72 + j] = f2bs(val);
            }
        }
        __syncthreads();

        // ---- softmax in-place on pls (all 256 threads) ----
        {
            float p0 = bs2f(pls[si * 72 + sjg]);
            float p1 = bs2f(pls[si * 72 + sjg + 16]);
            float p2 = bs2f(pls[si * 72 + sjg + 32]);
            float mx = fmaxf(p0, fmaxf(p1, p2));
            #pragma unroll
            for (int m = 1; m < 16; m <<= 1) mx = fmaxf(mx, __shfl_xor(mx, m));
            p0 = __expf(p0 - mx); p1 = __expf(p1 - mx); p2 = __expf(p2 - mx);
            float sum = p0 + p1 + p2;
            #pragma unroll
            for (int m = 1; m < 16; m <<= 1) sum += __shfl_xor(sum, m);
            float inv = 1.f / sum;
            pls[si * 72 + sjg]      = f2bs(p0 * inv);
            pls[si * 72 + sjg + 16] = f2bs(p1 * inv);
            pls[si * 72 + sjg + 32] = f2bs(p2 * inv);
        }
        __syncthreads();

        // ---- PV via MFMA: wave w owns d-tile w: d = w*16 + r ----
        {
            f32x4 o_acc = {0.f, 0.f, 0.f, 0.f};
            #pragma unroll
            for (int s = 0; s < 2; ++s) {
                bf16x8 a = *reinterpret_cast<const bf16x8*>(
                    pls + r * 72 + s * 32 + kg * 8);
                bf16x8 b = *reinterpret_cast<const bf16x8*>(
                    vls_T + (w * 16 + r) * 72 + s * 32 + kg * 8);
                o_acc = __builtin_amdgcn_mfma_f32_16x16x32_bf16(a, b, o_acc, 0, 0, 0);
            }
            #pragma unroll
            for (int reg = 0; reg < 4; ++reg) {
                int i = kg * 4 + reg;
                int y = wy * 4 + (i >> 2), x = wx * 4 + (i & 3);
                ao[((bb * 128 + y) * 128 + x) * 512 + h * 64 + w * 16 + r] = f2bs(o_acc[reg]);
            }
        }
        __syncthreads();   // protect kls/vls_T/pls before next head
    }
}

// --------------- 3x3 conv, IC=512 -> OC=64 via MFMA (out conv) -------------
__global__ __launch_bounds__(256) void conv512_kernel(
    const unsigned short* __restrict__ in,
    const unsigned short* __restrict__ wp,    // (64, 4608) bf16
    float* __restrict__ out)
{
    __shared__ __align__(16) unsigned short patch[100 * 72];
    const int tid = threadIdx.x, lane = tid & 63, w = tid >> 6;
    const int tx = blockIdx.x & 15, ty = blockIdx.x >> 4;
    const int img = blockIdx.y;
    const int gx0 = tx * 8 - 1, gy0 = ty * 8 - 1;
    const int r = lane & 15, kg = lane >> 4;

    f32x4 acc0 = {0.f,0.f,0.f,0.f}, acc1 = acc0, acc2 = acc0, acc3 = acc0;

    for (int ci = 0; ci < 8; ++ci) {
        __syncthreads();
        for (int u = tid; u < 800; u += 256) {
            int pos = u >> 3, seg = u & 7;
            int hy = pos / 10, hx = pos - hy * 10;
            int gy = gy0 + hy, gx = gx0 + hx;
            uint4 v = make_uint4(0u, 0u, 0u, 0u);
            if ((unsigned)gy < 128u && (unsigned)gx < 128u)
                v = *reinterpret_cast<const uint4*>(
                    in + (((size_t)img * 128 + gy) * 128 + gx) * 512 + ci * 64 + seg * 8);
            *reinterpret_cast<uint4*>(patch + pos * 72 + seg * 8) = v;
        }
        __syncthreads();
        #pragma unroll 3
        for (int kk = 0; kk < 18; ++kk) {
            int tap = kk >> 1, ic0 = (kk & 1) * 32;
            int ky = tap / 3, kx = tap - ky * 3;
            int oc = w * 16 + r;
            bf16x8 b = *reinterpret_cast<const bf16x8*>(
                wp + (size_t)oc * 4608 + ci * 576 + kk * 32 + kg * 8);
            #pragma unroll
            for (int m = 0; m < 4; ++m) {
                int rr = m * 16 + r;
                int pos = ((rr >> 3) + ky) * 10 + (rr & 7) + kx;
                bf16x8 a = *reinterpret_cast<const bf16x8*>(patch + pos * 72 + ic0 + kg * 8);
                f32x4& acc = (m == 0) ? acc0 : (m == 1) ? acc1 : (m == 2) ? acc2 : acc3;
                acc = __builtin_amdgcn_mfma_f32_16x16x32_bf16(a, b, acc, 0, 0, 0);
            }
        }
    }
    const int oc = w * 16 + r;
    #pragma unroll
    for (int m = 0; m < 4; ++m) {
        const f32x4& acc = (m == 0) ? acc0 : (m == 1) ? acc1 : (m == 2) ? acc2 : acc3;
        int r0 = m * 16 + kg * 4;
        int gy = ty * 8 + (r0 >> 3), gx = tx * 8 + (r0 & 7);
        *reinterpret_cast<float4*>(
            out + (((size_t)img * 64 + oc) * 128 + gy) * 128 + gx) =
            make_float4(acc[0], acc[1], acc[2], acc[3]);
    }
}

// ---------------------------------------------------------------------------
extern "C" void kernel_launch(void* const* d_in, const int* in_sizes, int n_in,
                              void* d_out, int out_size, void* d_ws, size_t ws_size,
                              hipStream_t stream)
{
    const float* q_inp  = (const float*)d_in[0];
    const float* k_inp  = (const float*)d_in[1];
    const float* flow_f = (const float*)d_in[2];
    const float* flow_b = (const float*)d_in[3];
    const float* gq     = (const float*)d_in[4];
    const float* bq     = (const float*)d_in[5];
    const float* gkv    = (const float*)d_in[6];
    const float* bkv    = (const float*)d_in[7];
    const float* Wq     = (const float*)d_in[8];
    const float* Wkv    = (const float*)d_in[9];
    const float* Wout   = (const float*)d_in[10];
    const float* sa     = (const float*)d_in[11];

    if (ws_size < 55050240u) return;

    char* ws = (char*)d_ws;
    unsigned short* qn   = (unsigned short*)(ws + 0);
    unsigned short* kvn  = (unsigned short*)(ws + 4194304);
    unsigned short* ao   = (unsigned short*)(ws + 16777216);
    unsigned short* wqb  = (unsigned short*)(ws + 50331648);
    unsigned short* wkvb = (unsigned short*)(ws + 50921472);
    unsigned short* wopb = (unsigned short*)(ws + 52101120);

    ln_q_kernel<<<8192, 256, 0, stream>>>(q_inp, gq, bq, qn);
    warp_ln_kv_kernel<<<24576, 256, 0, stream>>>(k_inp, flow_f, flow_b, gkv, bkv, kvn);

    repack_bf16_kernel<<<1152, 256, 0, stream>>>(Wq,   wqb,  64,  294912);
    repack_bf16_kernel<<<2304, 256, 0, stream>>>(Wkv,  wkvb, 64,  589824);
    repack_bf16_kernel<<<1152, 256, 0, stream>>>(Wout, wopb, 512, 294912);

    fused_attn_kernel<<<dim3(1024, 2), 256, 0, stream>>>(qn, kvn, wqb, wkvb, sa, ao);

    conv512_kernel<<<dim3(256, 2), 256, 0, stream>>>(ao, wopb, (float*)d_out);
}